// Round 2
// baseline (4634.275 us; speedup 1.0000x reference)
//
#include <hip/hip_runtime.h>
#include <hip/hip_bf16.h>
#include <math.h>

// Problem dims
#define DD 384
#define NHD 8
#define DHD 48
#define LL 4
#define NB 32768
#define FFH 1536
#define LDA 416   // bf16 stride: 416*2B = 208 dwords == 16 mod 32 -> optimal 8-window spread for ds_read_b128
#define LDS2 408  // k2 LN staging stride (fits exactly in qkv+oh union)
#define LDP 388   // fp32 pooled stride
#define EPS 1e-5f

typedef short bf16x8 __attribute__((ext_vector_type(8)));
typedef float f32x4 __attribute__((ext_vector_type(4)));
typedef unsigned short u16;
typedef unsigned int u32;

__device__ __forceinline__ u16 f2b(float f){           // fp32 -> bf16 RNE
  u32 u = __builtin_bit_cast(u32, f);
  u += 0x7FFFu + ((u >> 16) & 1u);
  return (u16)(u >> 16);
}
__device__ __forceinline__ float b2f(u16 h){ u32 u = ((u32)h) << 16; return __builtin_bit_cast(float, u); }

__device__ __forceinline__ bf16x8 ldfrag(const u16* p){
  uint4 q = *reinterpret_cast<const uint4*>(p);
  return __builtin_bit_cast(bf16x8, q);
}

// fp32 -> bf16 weight conversion (prepass; weights stay hot in L2/L3)
extern "C" __global__ void wconv(const float* __restrict__ src, u16* __restrict__ dst, int n){
  int i = blockIdx.x * 256 + threadIdx.x;
  if (i < n) dst[i] = f2b(src[i]);
}

// ---------------------------------------------------------------------------
// K1: cross-attn collapses to  h1[b,l,:] = LN1( (x@wv^T+bv)@wout^T+bout + lat[l] )
// Single LDS region [64][LDA] reused: x -> v -> ca.  53.2 KB -> 2 blocks/CU.
// ---------------------------------------------------------------------------
extern "C" __global__ void __launch_bounds__(512, 4)
k1_ca(const float* __restrict__ x, const float* __restrict__ latents,
      const float* __restrict__ ca_b_in, const float* __restrict__ ca_b_out,
      const float* __restrict__ n1g, const float* __restrict__ n1b,
      const u16* __restrict__ wv, const u16* __restrict__ wout,
      u16* __restrict__ h1g)
{
  extern __shared__ char smem[];
  u16* xb = (u16*)smem;           // [64][LDA], reused for v then ca
  const int tid = threadIdx.x, lane = tid & 63, w = tid >> 6;
  const int lr = lane & 15, lk = lane >> 4;
  const int b0 = blockIdx.x * 64;

  for (int i = tid; i < 64 * 96; i += 512){
    int r = i / 96, c4 = i % 96;
    float4 f = reinterpret_cast<const float4*>(x + (size_t)(b0 + r) * DD)[c4];
    u16* d = &xb[r * LDA + c4 * 4];
    d[0] = f2b(f.x); d[1] = f2b(f.y); d[2] = f2b(f.z); d[3] = f2b(f.w);
  }
  __syncthreads();

  const int m0 = (w & 3) * 16, nh = w >> 2;

  bf16x8 af[12];
  { const u16* ap = &xb[(m0 + lr) * LDA + lk * 8];
    #pragma unroll
    for (int kk = 0; kk < 12; kk++) af[kk] = ldfrag(ap + kk * 32); }
  __syncthreads();   // everyone's x fragments loaded -> region writable

  // GEMM1: v = x@wv^T + bv  (written into xb region)
  for (int nt = nh * 12; nt < nh * 12 + 12; nt++){
    int n0 = nt * 16;
    f32x4 acc = {0.f, 0.f, 0.f, 0.f};
    const u16* bp = &wv[(size_t)(n0 + lr) * DD + lk * 8];
    #pragma unroll
    for (int kk = 0; kk < 12; kk++)
      acc = __builtin_amdgcn_mfma_f32_16x16x32_bf16(af[kk], ldfrag(bp + kk * 32), acc, 0, 0, 0);
    float bias = ca_b_in[768 + n0 + lr];
    #pragma unroll
    for (int r = 0; r < 4; r++)
      xb[(m0 + lk * 4 + r) * LDA + n0 + lr] = f2b(acc[r] + bias);
  }
  __syncthreads();

  bf16x8 af2[12];
  { const u16* ap = &xb[(m0 + lr) * LDA + lk * 8];
    #pragma unroll
    for (int kk = 0; kk < 12; kk++) af2[kk] = ldfrag(ap + kk * 32); }
  __syncthreads();   // v fragments loaded -> region writable

  // GEMM2: ca = v@wout^T + bout  (written into xb region)
  for (int nt = nh * 12; nt < nh * 12 + 12; nt++){
    int n0 = nt * 16;
    f32x4 acc = {0.f, 0.f, 0.f, 0.f};
    const u16* bp = &wout[(size_t)(n0 + lr) * DD + lk * 8];
    #pragma unroll
    for (int kk = 0; kk < 12; kk++)
      acc = __builtin_amdgcn_mfma_f32_16x16x32_bf16(af2[kk], ldfrag(bp + kk * 32), acc, 0, 0, 0);
    float bias = ca_b_out[n0 + lr];
    #pragma unroll
    for (int r = 0; r < 4; r++)
      xb[(m0 + lk * 4 + r) * LDA + n0 + lr] = f2b(acc[r] + bias);
  }
  __syncthreads();

  // LN1 over (ca + lat[l]) per (row,l); one wave per row-LN
  for (int idx = w; idx < 64 * LL; idx += 8){
    int l = idx >> 6, r = idx & 63;
    float vals[6]; float s1 = 0.f, s2 = 0.f;
    #pragma unroll
    for (int j = 0; j < 6; j++){
      int c = lane + 64 * j;
      float xv = b2f(xb[r * LDA + c]) + latents[l * DD + c];
      vals[j] = xv; s1 += xv; s2 += xv * xv;
    }
    #pragma unroll
    for (int off = 32; off > 0; off >>= 1){ s1 += __shfl_xor(s1, off); s2 += __shfl_xor(s2, off); }
    float mean = s1 * (1.f / DD);
    float var  = s2 * (1.f / DD) - mean * mean;
    float rstd = rsqrtf(var + EPS);
    size_t orow = ((size_t)(b0 + r) * LL + l) * DD;
    #pragma unroll
    for (int j = 0; j < 6; j++){
      int c = lane + 64 * j;
      h1g[orow + c] = f2b((vals[j] - mean) * rstd * n1g[c] + n1b[c]);
    }
  }
}

// ---------------------------------------------------------------------------
// K2: self-attn over L=4 + out-proj + residual + LN2 (in place on hg)
// Per-head out-proj accumulation in registers (K=48 zero-padded to 64) kills
// the ob staging tile.  LDS = qkv(fp32) + oh union'd with LN staging = 52.2 KB.
// ---------------------------------------------------------------------------
extern "C" __global__ void __launch_bounds__(512, 4)
k2_sa(const float* __restrict__ sa_b_in, const float* __restrict__ sa_b_out,
      const float* __restrict__ n2g, const float* __restrict__ n2b,
      const u16* __restrict__ wqkv, const u16* __restrict__ wo,
      u16* __restrict__ hg)
{
  extern __shared__ char smem[];
  float* qf = (float*)smem;                      // [64][52]
  float* kf = qf + 64 * 52;
  float* vf = kf + 64 * 52;
  u16*   oh = (u16*)(vf + 64 * 52);              // [64][96], cols 48..63 kept zero (k-pad)
  u16*   st = (u16*)smem;                        // [64][LDS2] LN staging (union over everything)
  const int tid = threadIdx.x, lane = tid & 63, w = tid >> 6;
  const int lr = lane & 15, lk = lane >> 4;
  const int b0 = blockIdx.x * 16;
  const size_t t0 = (size_t)b0 * 4;

  for (int i = tid; i < 64 * 96; i += 512) oh[i] = 0;   // zero once (incl. k-pad cols)

  const int m0 = (w & 3) * 16, nh = w >> 2;

  bf16x8 af[12];          // h1 M-tile fragments straight from global (L2)
  { const u16* ap = &hg[(t0 + m0 + lr) * DD + lk * 8];
    #pragma unroll
    for (int kk = 0; kk < 12; kk++) af[kk] = ldfrag(ap + kk * 32); }

  f32x4 oacc[12];
  #pragma unroll
  for (int i = 0; i < 12; i++) oacc[i] = {0.f, 0.f, 0.f, 0.f};
  __syncthreads();

  for (int hh = 0; hh < NHD; hh++){
    // qkv projections for this head (9 16-col tiles: q0..2,k0..2,v0..2)
    for (int nt = nh; nt < 9; nt += 2){
      int op = nt / 3, sub = nt % 3;
      int wrow = op * DD + hh * DHD + sub * 16;
      f32x4 acc = {0.f, 0.f, 0.f, 0.f};
      const u16* bp = &wqkv[(size_t)(wrow + lr) * DD + lk * 8];
      #pragma unroll 4
      for (int kk = 0; kk < 12; kk++)
        acc = __builtin_amdgcn_mfma_f32_16x16x32_bf16(af[kk], ldfrag(bp + kk * 32), acc, 0, 0, 0);
      float bias = sa_b_in[wrow + lr];
      float* dst = (op == 0) ? qf : (op == 1) ? kf : vf;
      int c = sub * 16 + lr;
      #pragma unroll
      for (int r = 0; r < 4; r++)
        dst[(m0 + lk * 4 + r) * 52 + c] = acc[r] + bias;
    }
    __syncthreads();
    // tiny attention: 32 threads per batch
    {
      int tb = tid >> 5, t = tid & 31;
      int qr = t & 3, cg = t >> 2;
      int rq = tb * 4 + qr;
      const float scale = 0.14433756729740643f;  // 1/sqrt(48)
      float s[4];
      #pragma unroll
      for (int kl = 0; kl < 4; kl++){
        float acc = 0.f;
        const float* qp = &qf[rq * 52];
        const float* kp = &kf[(tb * 4 + kl) * 52];
        #pragma unroll
        for (int d2 = 0; d2 < 48; d2++) acc += qp[d2] * kp[d2];
        s[kl] = acc * scale;
      }
      float m = fmaxf(fmaxf(s[0], s[1]), fmaxf(s[2], s[3]));
      float e0 = expf(s[0] - m), e1 = expf(s[1] - m), e2 = expf(s[2] - m), e3 = expf(s[3] - m);
      float rs = 1.f / (e0 + e1 + e2 + e3);
      #pragma unroll
      for (int cc = 0; cc < 6; cc++){
        int c = cg * 6 + cc;
        float o = e0 * rs * vf[(tb * 4 + 0) * 52 + c] + e1 * rs * vf[(tb * 4 + 1) * 52 + c]
                + e2 * rs * vf[(tb * 4 + 2) * 52 + c] + e3 * rs * vf[(tb * 4 + 3) * 52 + c];
        oh[rq * 96 + c] = f2b(o);
      }
    }
    __syncthreads();
    // out-proj accumulate for this head: oacc += o_h @ wo[:, h*48:(h+1)*48]^T
    #pragma unroll
    for (int kk2 = 0; kk2 < 2; kk2++){
      bf16x8 a2 = ldfrag(&oh[(m0 + lr) * 96 + kk2 * 32 + lk * 8]);
      #pragma unroll
      for (int nt = 0; nt < 12; nt++){
        int n0 = nh * 192 + nt * 16;
        oacc[nt] = __builtin_amdgcn_mfma_f32_16x16x32_bf16(
                     a2, ldfrag(&wo[(size_t)(n0 + lr) * DD + hh * DHD + kk2 * 32 + lk * 8]),
                     oacc[nt], 0, 0, 0);
      }
    }
    __syncthreads();
  }
  // + bias + residual -> staging
  #pragma unroll
  for (int nt = 0; nt < 12; nt++){
    int c = nh * 192 + nt * 16 + lr;
    float bias = sa_b_out[c];
    #pragma unroll
    for (int r = 0; r < 4; r++){
      int row = m0 + lk * 4 + r;
      float v = oacc[nt][r] + bias + b2f(hg[(t0 + row) * DD + c]);
      st[row * LDS2 + c] = f2b(v);
    }
  }
  __syncthreads();
  // LN2 -> global (in-place h buffer)
  for (int r = w; r < 64; r += 8){
    float vals[6]; float s1 = 0.f, s2 = 0.f;
    #pragma unroll
    for (int j = 0; j < 6; j++){
      int c = lane + 64 * j;
      float xv = b2f(st[r * LDS2 + c]);
      vals[j] = xv; s1 += xv; s2 += xv * xv;
    }
    #pragma unroll
    for (int off = 32; off > 0; off >>= 1){ s1 += __shfl_xor(s1, off); s2 += __shfl_xor(s2, off); }
    float mean = s1 * (1.f / DD), var = s2 * (1.f / DD) - mean * mean, rstd = rsqrtf(var + EPS);
    #pragma unroll
    for (int j = 0; j < 6; j++){
      int c = lane + 64 * j;
      hg[(t0 + r) * DD + c] = f2b((vals[j] - mean) * rstd * n2g[c] + n2b[c]);
    }
  }
}

// ---------------------------------------------------------------------------
// K3: FFN (hidden chunked by 256) + LN3 + pool + gate.
// A-fragments from global; tc tile [64][LDA] reused as pre-LN3 staging; fp32
// pool buffer overlays tc.  LDS = 66.5 KB -> 2 blocks/CU.
// ---------------------------------------------------------------------------
extern "C" __global__ void __launch_bounds__(512, 4)
k3_ffn(const float* __restrict__ ffn_b1, const float* __restrict__ ffn_b2,
       const float* __restrict__ n3g, const float* __restrict__ n3b,
       const float* __restrict__ gate_b,
       const u16* __restrict__ w1, const u16* __restrict__ w2, const u16* __restrict__ wg,
       const u16* __restrict__ hg, float* __restrict__ out)
{
  extern __shared__ char smem[];
  u16*   tcb = (u16*)smem;                       // [64][LDA]: gelu chunk (cols 0..255), then pre-LN3 (cols 0..383)
  u16*   pb  = tcb + 64 * LDA;                   // [16][LDA] pooled bf16
  float* pf  = (float*)smem;                     // [16][LDP] pooled fp32 (overlays tcb after pooling)
  const int tid = threadIdx.x, lane = tid & 63, w = tid >> 6;
  const int lr = lane & 15, lk = lane >> 4;
  const int b0 = blockIdx.x * 16;
  const size_t t0 = (size_t)b0 * 4;

  const int m0 = (w & 3) * 16, nh = w >> 6 ? 0 : (w >> 2);   // nh = w>>2

  bf16x8 af[12];
  { const u16* ap = &hg[(t0 + m0 + lr) * DD + lk * 8];
    #pragma unroll
    for (int kk = 0; kk < 12; kk++) af[kk] = ldfrag(ap + kk * 32); }

  f32x4 ffacc[12];
  #pragma unroll
  for (int i = 0; i < 12; i++) ffacc[i] = {0.f, 0.f, 0.f, 0.f};

  for (int fc = 0; fc < 6; fc++){
    // GEMM-A: tc = gelu(h @ w1_chunk^T + b1), 2 N-tiles at a time
    #pragma unroll 1
    for (int tg = 0; tg < 4; tg++){
      f32x4 tacc[2];
      tacc[0] = {0.f, 0.f, 0.f, 0.f}; tacc[1] = {0.f, 0.f, 0.f, 0.f};
      #pragma unroll
      for (int kk = 0; kk < 12; kk++){
        #pragma unroll
        for (int j = 0; j < 2; j++){
          int hrow = fc * 256 + (nh * 8 + tg * 2 + j) * 16 + lr;
          tacc[j] = __builtin_amdgcn_mfma_f32_16x16x32_bf16(
                      af[kk], ldfrag(&w1[(size_t)hrow * DD + kk * 32 + lk * 8]), tacc[j], 0, 0, 0);
        }
      }
      #pragma unroll
      for (int j = 0; j < 2; j++){
        int cl = (nh * 8 + tg * 2 + j) * 16 + lr;
        float bias = ffn_b1[fc * 256 + cl];
        #pragma unroll
        for (int r = 0; r < 4; r++){
          float v = tacc[j][r] + bias;
          float g = 0.5f * v * (1.f + erff(v * 0.70710678118f));   // exact gelu
          tcb[(m0 + lk * 4 + r) * LDA + cl] = f2b(g);
        }
      }
    }
    __syncthreads();
    // GEMM-B: ffacc += tc @ w2_chunk^T
    #pragma unroll 2
    for (int kk = 0; kk < 8; kk++){
      bf16x8 a2 = ldfrag(&tcb[(m0 + lr) * LDA + kk * 32 + lk * 8]);
      #pragma unroll
      for (int nt = 0; nt < 12; nt++){
        int n0 = nh * 192 + nt * 16;
        ffacc[nt] = __builtin_amdgcn_mfma_f32_16x16x32_bf16(
                      a2, ldfrag(&w2[(size_t)(n0 + lr) * FFH + fc * 256 + kk * 32 + lk * 8]),
                      ffacc[nt], 0, 0, 0);
      }
    }
    __syncthreads();
  }
  // + b2 + residual(global re-read) -> pre-LN3 staged into tcb
  #pragma unroll
  for (int nt = 0; nt < 12; nt++){
    int c = nh * 192 + nt * 16 + lr;
    float b2v = ffn_b2[c];
    #pragma unroll
    for (int r = 0; r < 4; r++){
      int row = m0 + lk * 4 + r;
      float v = ffacc[nt][r] + b2v + b2f(hg[(t0 + row) * DD + c]);
      tcb[row * LDA + c] = f2b(v);
    }
  }
  __syncthreads();
  // LN3 + pool: wave w owns rows 8w..8w+7 (= batches 2w, 2w+1); h3 never materialized
  float pol[2][6];
  #pragma unroll
  for (int p = 0; p < 2; p++)
    #pragma unroll
    for (int j = 0; j < 6; j++) pol[p][j] = 0.f;
  #pragma unroll
  for (int rr = 0; rr < 8; rr++){
    int row = w * 8 + rr;
    float vals[6]; float s1 = 0.f, s2 = 0.f;
    #pragma unroll
    for (int j = 0; j < 6; j++){
      int c = lane + 64 * j;
      float xv = b2f(tcb[row * LDA + c]);
      vals[j] = xv; s1 += xv; s2 += xv * xv;
    }
    #pragma unroll
    for (int off = 32; off > 0; off >>= 1){ s1 += __shfl_xor(s1, off); s2 += __shfl_xor(s2, off); }
    float mean = s1 * (1.f / DD), var = s2 * (1.f / DD) - mean * mean, rstd = rsqrtf(var + EPS);
    #pragma unroll
    for (int j = 0; j < 6; j++){
      int c = lane + 64 * j;
      pol[rr >> 2][j] += 0.25f * ((vals[j] - mean) * rstd * n3g[c] + n3b[c]);
    }
  }
  __syncthreads();   // all tcb reads done -> pf overlay is safe
  #pragma unroll
  for (int p = 0; p < 2; p++){
    int batch = w * 2 + p;
    #pragma unroll
    for (int j = 0; j < 6; j++){
      int c = lane + 64 * j;
      pb[batch * LDA + c] = f2b(pol[p][j]);
      pf[batch * LDP + c] = pol[p][j];
    }
  }
  __syncthreads();
  // gate gemm (M=16) + sigmoid + multiply + store fp32
  {
    bf16x8 ag[12];
    const u16* ap = &pb[lr * LDA + lk * 8];
    #pragma unroll
    for (int kk = 0; kk < 12; kk++) ag[kk] = ldfrag(ap + kk * 32);
    for (int nt = w * 3; nt < w * 3 + 3; nt++){
      int n0 = nt * 16;
      f32x4 acc = {0.f, 0.f, 0.f, 0.f};
      const u16* bp = &wg[(size_t)(n0 + lr) * DD + lk * 8];
      #pragma unroll
      for (int kk = 0; kk < 12; kk++)
        acc = __builtin_amdgcn_mfma_f32_16x16x32_bf16(ag[kk], ldfrag(bp + kk * 32), acc, 0, 0, 0);
      float gbv = gate_b[n0 + lr];
      #pragma unroll
      for (int r = 0; r < 4; r++){
        int batch = lk * 4 + r;
        float g = 1.f / (1.f + expf(-(acc[r] + gbv)));
        out[(size_t)(b0 + batch) * DD + n0 + lr] = pf[batch * LDP + n0 + lr] * g;
      }
    }
  }
}

// ---------------------------------------------------------------------------
// host launch
// ---------------------------------------------------------------------------
#define OFF_WV     0
#define OFF_WOUT   147456
#define OFF_SAWIN  294912
#define OFF_SAWOUT 737280
#define OFF_W1     884736
#define OFF_W2     1474560
#define OFF_WG     2064384
#define OFF_H      2211840   // ushort index; h buffer: 32768*4*384 bf16

extern "C" void kernel_launch(void* const* d_in, const int* in_sizes, int n_in,
                              void* d_out, int out_size, void* d_ws, size_t ws_size,
                              hipStream_t stream)
{
  const float* x        = (const float*)d_in[0];
  const float* latents  = (const float*)d_in[1];
  const float* ca_w_in  = (const float*)d_in[2];
  const float* ca_b_in  = (const float*)d_in[3];
  const float* ca_w_out = (const float*)d_in[4];
  const float* ca_b_out = (const float*)d_in[5];
  const float* sa_w_in  = (const float*)d_in[6];
  const float* sa_b_in  = (const float*)d_in[7];
  const float* sa_w_out = (const float*)d_in[8];
  const float* sa_b_out = (const float*)d_in[9];
  const float* n1g = (const float*)d_in[10];
  const float* n1b = (const float*)d_in[11];
  const float* n2g = (const float*)d_in[12];
  const float* n2b = (const float*)d_in[13];
  const float* n3g = (const float*)d_in[14];
  const float* n3b = (const float*)d_in[15];
  const float* w1f = (const float*)d_in[16];
  const float* b1  = (const float*)d_in[17];
  const float* w2f = (const float*)d_in[18];
  const float* b2  = (const float*)d_in[19];
  const float* wgf = (const float*)d_in[20];
  const float* gb  = (const float*)d_in[21];

  u16* ws = (u16*)d_ws;
  u16* wv     = ws + OFF_WV;
  u16* wout   = ws + OFF_WOUT;
  u16* sawin  = ws + OFF_SAWIN;
  u16* sawout = ws + OFF_SAWOUT;
  u16* w1     = ws + OFF_W1;
  u16* w2     = ws + OFF_W2;
  u16* wg     = ws + OFF_WG;
  u16* h      = ws + OFF_H;

  wconv<<<dim3((147456 + 255) / 256), dim3(256), 0, stream>>>(ca_w_in + 768 * 384, wv, 147456);
  wconv<<<dim3((147456 + 255) / 256), dim3(256), 0, stream>>>(ca_w_out, wout, 147456);
  wconv<<<dim3((442368 + 255) / 256), dim3(256), 0, stream>>>(sa_w_in, sawin, 442368);
  wconv<<<dim3((147456 + 255) / 256), dim3(256), 0, stream>>>(sa_w_out, sawout, 147456);
  wconv<<<dim3((589824 + 255) / 256), dim3(256), 0, stream>>>(w1f, w1, 589824);
  wconv<<<dim3((589824 + 255) / 256), dim3(256), 0, stream>>>(w2f, w2, 589824);
  wconv<<<dim3((147456 + 255) / 256), dim3(256), 0, stream>>>(wgf, wg, 147456);

  const int SM1 = 64 * LDA * 2;                       // 53248
  const int SM2 = 3 * 64 * 52 * 4 + 64 * 96 * 2;      // 52224 (== 64*LDS2*2 staging union)
  const int SM3 = 64 * LDA * 2 + 16 * LDA * 2;        // 66560
  (void)hipFuncSetAttribute((const void*)k1_ca,  hipFuncAttributeMaxDynamicSharedMemorySize, SM1);
  (void)hipFuncSetAttribute((const void*)k2_sa,  hipFuncAttributeMaxDynamicSharedMemorySize, SM2);
  (void)hipFuncSetAttribute((const void*)k3_ffn, hipFuncAttributeMaxDynamicSharedMemorySize, SM3);

  k1_ca<<<dim3(512),  dim3(512), SM1, stream>>>(x, latents, ca_b_in, ca_b_out, n1g, n1b, wv, wout, h);
  k2_sa<<<dim3(2048), dim3(512), SM2, stream>>>(sa_b_in, sa_b_out, n2g, n2b, sawin, sawout, h);
  k3_ffn<<<dim3(2048), dim3(512), SM3, stream>>>(b1, b2, n3g, n3b, gb, w1, w2, wg, h, (float*)d_out);

  (void)in_sizes; (void)n_in; (void)out_size; (void)ws_size;
}

// Round 3
// 4623.674 us; speedup vs baseline: 1.0023x; 1.0023x over previous
//
#include <hip/hip_runtime.h>
#include <hip/hip_bf16.h>
#include <math.h>

// Problem dims
#define DD 384
#define NHD 8
#define DHD 48
#define LL 4
#define NB 32768
#define FFH 1536
#define LDA 392   // 196 dw == 4 mod 32 -> ds_read_b128 over 16 rows = 2-way (free)
#define LDQ 56    // qkv bf16 stride
#define LDF 260   // tcb stride (130 dw == 2 mod 32 -> ~2-way)
#define LDPB 392  // pooled bf16 stride
#define LDPF 388  // pooled fp32 stride
#define EPS 1e-5f

typedef short bf16x8 __attribute__((ext_vector_type(8)));
typedef float f32x4 __attribute__((ext_vector_type(4)));
typedef unsigned short u16;
typedef unsigned int u32;

__device__ __forceinline__ u16 f2b(float f){           // fp32 -> bf16 RNE
  u32 u = __builtin_bit_cast(u32, f);
  u += 0x7FFFu + ((u >> 16) & 1u);
  return (u16)(u >> 16);
}
__device__ __forceinline__ float b2f(u16 h){ u32 u = ((u32)h) << 16; return __builtin_bit_cast(float, u); }

__device__ __forceinline__ bf16x8 ldfrag(const u16* p){
  uint4 q = *reinterpret_cast<const uint4*>(p);
  return __builtin_bit_cast(bf16x8, q);
}

// fp32 -> bf16 weight conversion (prepass; weights stay hot in L2/L3)
extern "C" __global__ void wconv(const float* __restrict__ src, u16* __restrict__ dst, int n){
  int i = blockIdx.x * 256 + threadIdx.x;
  if (i < n) dst[i] = f2b(src[i]);
}

// ---------------------------------------------------------------------------
// K1: cross-attn collapses to  h1[b,l,:] = LN1( (x@wv^T+bv)@wout^T+bout + lat[l] )
// Single LDS region [64][LDA] reused: x -> v -> ca.  50 KB, <=128 VGPR, 2 blk/CU.
// ---------------------------------------------------------------------------
extern "C" __global__ void __launch_bounds__(512, 4)
k1_ca(const float* __restrict__ x, const float* __restrict__ latents,
      const float* __restrict__ ca_b_in, const float* __restrict__ ca_b_out,
      const float* __restrict__ n1g, const float* __restrict__ n1b,
      const u16* __restrict__ wv, const u16* __restrict__ wout,
      u16* __restrict__ h1g)
{
  extern __shared__ char smem[];
  u16* xb = (u16*)smem;           // [64][LDA], reused for v then ca
  const int tid = threadIdx.x, lane = tid & 63, w = tid >> 6;
  const int lr = lane & 15, lk = lane >> 4;
  const int b0 = blockIdx.x * 64;

  for (int i = tid; i < 64 * 96; i += 512){
    int r = i / 96, c4 = i % 96;
    float4 f = reinterpret_cast<const float4*>(x + (size_t)(b0 + r) * DD)[c4];
    u16* d = &xb[r * LDA + c4 * 4];
    d[0] = f2b(f.x); d[1] = f2b(f.y); d[2] = f2b(f.z); d[3] = f2b(f.w);
  }
  __syncthreads();

  const int m0 = (w & 3) * 16, nh = w >> 2;

  // GEMM1: v = x@wv^T + bv  (a-frags loaded per N-tile straight from LDS)
  {
    bf16x8 af[12];
    const u16* ap = &xb[(m0 + lr) * LDA + lk * 8];
    #pragma unroll
    for (int kk = 0; kk < 12; kk++) af[kk] = ldfrag(ap + kk * 32);
    __syncthreads();   // fragments in regs -> region writable
    for (int nt = nh * 12; nt < nh * 12 + 12; nt++){
      int n0 = nt * 16;
      f32x4 acc = {0.f, 0.f, 0.f, 0.f};
      const u16* bp = &wv[(size_t)(n0 + lr) * DD + lk * 8];
      #pragma unroll
      for (int kk = 0; kk < 12; kk++)
        acc = __builtin_amdgcn_mfma_f32_16x16x32_bf16(af[kk], ldfrag(bp + kk * 32), acc, 0, 0, 0);
      float bias = ca_b_in[768 + n0 + lr];
      #pragma unroll
      for (int r = 0; r < 4; r++)
        xb[(m0 + lk * 4 + r) * LDA + n0 + lr] = f2b(acc[r] + bias);
    }
  }
  __syncthreads();
  // GEMM2: ca = v@wout^T + bout
  {
    bf16x8 af[12];
    const u16* ap = &xb[(m0 + lr) * LDA + lk * 8];
    #pragma unroll
    for (int kk = 0; kk < 12; kk++) af[kk] = ldfrag(ap + kk * 32);
    __syncthreads();
    for (int nt = nh * 12; nt < nh * 12 + 12; nt++){
      int n0 = nt * 16;
      f32x4 acc = {0.f, 0.f, 0.f, 0.f};
      const u16* bp = &wout[(size_t)(n0 + lr) * DD + lk * 8];
      #pragma unroll
      for (int kk = 0; kk < 12; kk++)
        acc = __builtin_amdgcn_mfma_f32_16x16x32_bf16(af[kk], ldfrag(bp + kk * 32), acc, 0, 0, 0);
      float bias = ca_b_out[n0 + lr];
      #pragma unroll
      for (int r = 0; r < 4; r++)
        xb[(m0 + lk * 4 + r) * LDA + n0 + lr] = f2b(acc[r] + bias);
    }
  }
  __syncthreads();

  // LN1 over (ca + lat[l]) per (row,l); one wave per row-LN
  for (int idx = w; idx < 64 * LL; idx += 8){
    int l = idx >> 6, r = idx & 63;
    float vals[6]; float s1 = 0.f, s2 = 0.f;
    #pragma unroll
    for (int j = 0; j < 6; j++){
      int c = lane + 64 * j;
      float xv = b2f(xb[r * LDA + c]) + latents[l * DD + c];
      vals[j] = xv; s1 += xv; s2 += xv * xv;
    }
    #pragma unroll
    for (int off = 32; off > 0; off >>= 1){ s1 += __shfl_xor(s1, off); s2 += __shfl_xor(s2, off); }
    float mean = s1 * (1.f / DD);
    float var  = s2 * (1.f / DD) - mean * mean;
    float rstd = rsqrtf(var + EPS);
    size_t orow = ((size_t)(b0 + r) * LL + l) * DD;
    #pragma unroll
    for (int j = 0; j < 6; j++){
      int c = lane + 64 * j;
      h1g[orow + c] = f2b((vals[j] - mean) * rstd * n1g[c] + n1b[c]);
    }
  }
}

// ---------------------------------------------------------------------------
// K2: self-attn over L=4 + out-proj + residual + LN2 (in place on hg)
// Head loop fills oh[64][392] (bf16 attn output); out-proj is ONE K=384 GEMM
// afterwards, so af[12] and oacc[12] are never live together (<=128 VGPR).
// LDS = qkv bf16 (21 KB) + oh (49 KB) = 70 KB -> 2 blocks/CU.
// ---------------------------------------------------------------------------
extern "C" __global__ void __launch_bounds__(512, 4)
k2_sa(const float* __restrict__ sa_b_in, const float* __restrict__ sa_b_out,
      const float* __restrict__ n2g, const float* __restrict__ n2b,
      const u16* __restrict__ wqkv, const u16* __restrict__ wo,
      u16* __restrict__ hg)
{
  extern __shared__ char smem[];
  u16* qb = (u16*)smem;                 // [64][LDQ] bf16
  u16* kb = qb + 64 * LDQ;
  u16* vb = kb + 64 * LDQ;
  u16* oh = vb + 64 * LDQ;              // [64][LDA] attn output bf16
  u16* st = (u16*)smem;                 // [64][LDA] pre-LN2 staging (overlay, used after oh dead)
  const int tid = threadIdx.x, lane = tid & 63, w = tid >> 6;
  const int lr = lane & 15, lk = lane >> 4;
  const int b0 = blockIdx.x * 16;
  const size_t t0 = (size_t)b0 * 4;

  const int m0 = (w & 3) * 16, ng = w >> 2;

  {
    bf16x8 af[12];          // h1 M-tile fragments straight from global (L2)
    { const u16* ap = &hg[(t0 + m0 + lr) * DD + lk * 8];
      #pragma unroll
      for (int kk = 0; kk < 12; kk++) af[kk] = ldfrag(ap + kk * 32); }

    for (int hh = 0; hh < NHD; hh++){
      // qkv projections for this head (9 16-col tiles: q0..2,k0..2,v0..2)
      for (int nt = ng; nt < 9; nt += 2){
        int op = nt / 3, sub = nt % 3;
        int wrow = op * DD + hh * DHD + sub * 16;
        f32x4 acc = {0.f, 0.f, 0.f, 0.f};
        const u16* bp = &wqkv[(size_t)(wrow + lr) * DD + lk * 8];
        #pragma unroll 4
        for (int kk = 0; kk < 12; kk++)
          acc = __builtin_amdgcn_mfma_f32_16x16x32_bf16(af[kk], ldfrag(bp + kk * 32), acc, 0, 0, 0);
        float bias = sa_b_in[wrow + lr];
        u16* dst = (op == 0) ? qb : (op == 1) ? kb : vb;
        int c = sub * 16 + lr;
        #pragma unroll
        for (int r = 0; r < 4; r++)
          dst[(m0 + lk * 4 + r) * LDQ + c] = f2b(acc[r] + bias);
      }
      __syncthreads();
      // tiny attention: 32 threads per batch (tb), bf16 q/k/v
      {
        int tb = tid >> 5, t = tid & 31;
        int qr = t & 3, cg = t >> 2;
        int rq = tb * 4 + qr;
        const float scale = 0.14433756729740643f;  // 1/sqrt(48)
        float s[4];
        #pragma unroll
        for (int kl = 0; kl < 4; kl++){
          float acc = 0.f;
          const u16* qp = &qb[rq * LDQ];
          const u16* kp = &kb[(tb * 4 + kl) * LDQ];
          #pragma unroll
          for (int d2 = 0; d2 < 24; d2++){
            u32 qu = *reinterpret_cast<const u32*>(qp + 2 * d2);
            u32 ku = *reinterpret_cast<const u32*>(kp + 2 * d2);
            acc += b2f((u16)qu) * b2f((u16)ku)
                 + b2f((u16)(qu >> 16)) * b2f((u16)(ku >> 16));
          }
          s[kl] = acc * scale;
        }
        float m = fmaxf(fmaxf(s[0], s[1]), fmaxf(s[2], s[3]));
        float e0 = expf(s[0] - m), e1 = expf(s[1] - m), e2 = expf(s[2] - m), e3 = expf(s[3] - m);
        float rs = 1.f / (e0 + e1 + e2 + e3);
        #pragma unroll
        for (int cc = 0; cc < 6; cc++){
          int c = cg * 6 + cc;
          float o = e0 * rs * b2f(vb[(tb * 4 + 0) * LDQ + c]) + e1 * rs * b2f(vb[(tb * 4 + 1) * LDQ + c])
                  + e2 * rs * b2f(vb[(tb * 4 + 2) * LDQ + c]) + e3 * rs * b2f(vb[(tb * 4 + 3) * LDQ + c]);
          oh[rq * LDA + hh * DHD + c] = f2b(o);
        }
      }
      __syncthreads();
    }
  } // af dies here

  // out-proj: ONE GEMM, K=384, A from oh (LDS), oacc[12] persistent
  f32x4 oacc[12];
  #pragma unroll
  for (int i = 0; i < 12; i++) oacc[i] = {0.f, 0.f, 0.f, 0.f};
  #pragma unroll 2
  for (int kk = 0; kk < 12; kk++){
    bf16x8 a2 = ldfrag(&oh[(m0 + lr) * LDA + kk * 32 + lk * 8]);
    #pragma unroll
    for (int nt = 0; nt < 12; nt++){
      int n0 = ng * 192 + nt * 16;
      oacc[nt] = __builtin_amdgcn_mfma_f32_16x16x32_bf16(
                   a2, ldfrag(&wo[(size_t)(n0 + lr) * DD + kk * 32 + lk * 8]), oacc[nt], 0, 0, 0);
    }
  }
  __syncthreads();   // all oh reads done -> st overlay safe

  // + bias + residual (global re-read) -> st
  #pragma unroll
  for (int nt = 0; nt < 12; nt++){
    int c = ng * 192 + nt * 16 + lr;
    float bias = sa_b_out[c];
    #pragma unroll
    for (int r = 0; r < 4; r++){
      int row = m0 + lk * 4 + r;
      float v = oacc[nt][r] + bias + b2f(hg[(t0 + row) * DD + c]);
      st[row * LDA + c] = f2b(v);
    }
  }
  __syncthreads();
  // LN2 -> global (in-place h buffer)
  for (int r = w; r < 64; r += 8){
    float vals[6]; float s1 = 0.f, s2 = 0.f;
    #pragma unroll
    for (int j = 0; j < 6; j++){
      int c = lane + 64 * j;
      float xv = b2f(st[r * LDA + c]);
      vals[j] = xv; s1 += xv; s2 += xv * xv;
    }
    #pragma unroll
    for (int off = 32; off > 0; off >>= 1){ s1 += __shfl_xor(s1, off); s2 += __shfl_xor(s2, off); }
    float mean = s1 * (1.f / DD), var = s2 * (1.f / DD) - mean * mean, rstd = rsqrtf(var + EPS);
    #pragma unroll
    for (int j = 0; j < 6; j++){
      int c = lane + 64 * j;
      hg[(t0 + r) * DD + c] = f2b((vals[j] - mean) * rstd * n2g[c] + n2b[c]);
    }
  }
}

// ---------------------------------------------------------------------------
// K3: FFN (hidden chunked by 256) + LN3 + pool + gate.
// No ht tile: A-frags & residual straight from global (L2).  GEMM-A is
// k-outer/t-inner in two 4-tile halves (tacc[4]) so peak live regs stay
// under 128.  LN3+pool in registers w/ tiny cross-wave stats buffer.
// LDS = tcb 32.5 KB (pst/pf/pb overlay) -> 2 blocks/CU.
// ---------------------------------------------------------------------------
extern "C" __global__ void __launch_bounds__(512, 4)
k3_ffn(const float* __restrict__ ffn_b1, const float* __restrict__ ffn_b2,
       const float* __restrict__ n3g, const float* __restrict__ n3b,
       const float* __restrict__ gate_b,
       const u16* __restrict__ w1, const u16* __restrict__ w2, const u16* __restrict__ wg,
       const u16* __restrict__ hg, float* __restrict__ out)
{
  extern __shared__ char smem[];
  u16*   tcb = (u16*)smem;                        // [64][LDF] gelu chunk
  float* pst = (float*)smem;                      // [64][4] LN3 partial stats (overlay after tcb dead)
  float* pf  = (float*)(smem + 1024);             // [16][LDPF] pooled fp32
  u16*   pb  = (u16*)(smem + 1024 + 16 * LDPF * 4); // [16][LDPB] pooled bf16
  const int tid = threadIdx.x, lane = tid & 63, w = tid >> 6;
  const int lr = lane & 15, lk = lane >> 4;
  const int b0 = blockIdx.x * 16;
  const size_t t0 = (size_t)b0 * 4;

  const int m0 = (w & 3) * 16, nh = w >> 2;
  const u16* arow = &hg[(t0 + m0 + lr) * DD + lk * 8];   // A-frag base (global, L2-hot)

  f32x4 ffacc[12];
  #pragma unroll
  for (int i = 0; i < 12; i++) ffacc[i] = {0.f, 0.f, 0.f, 0.f};

  for (int fc = 0; fc < 6; fc++){
    // GEMM-A: tcb = gelu(h @ w1_chunk^T + b1); two halves of 4 N-tiles,
    // k-outer / t-inner so the A-frag is loaded once per kk.
    #pragma unroll 1
    for (int half = 0; half < 2; half++){
      f32x4 tacc[4];
      #pragma unroll
      for (int i = 0; i < 4; i++) tacc[i] = {0.f, 0.f, 0.f, 0.f};
      #pragma unroll 2
      for (int kk = 0; kk < 12; kk++){
        bf16x8 a = ldfrag(arow + kk * 32);
        #pragma unroll
        for (int t = 0; t < 4; t++){
          int hrow = fc * 256 + (nh * 8 + half * 4 + t) * 16 + lr;
          tacc[t] = __builtin_amdgcn_mfma_f32_16x16x32_bf16(
                      a, ldfrag(&w1[(size_t)hrow * DD + kk * 32 + lk * 8]), tacc[t], 0, 0, 0);
        }
      }
      #pragma unroll
      for (int t = 0; t < 4; t++){
        int cl = (nh * 8 + half * 4 + t) * 16 + lr;
        float bias = ffn_b1[fc * 256 + cl];
        #pragma unroll
        for (int r = 0; r < 4; r++){
          float v = tacc[t][r] + bias;
          float g = 0.5f * v * (1.f + erff(v * 0.70710678118f));   // exact gelu
          tcb[(m0 + lk * 4 + r) * LDF + cl] = f2b(g);
        }
      }
    }
    __syncthreads();
    // GEMM-B: ffacc += tcb @ w2_chunk^T
    #pragma unroll 2
    for (int kk = 0; kk < 8; kk++){
      bf16x8 a2 = ldfrag(&tcb[(m0 + lr) * LDF + kk * 32 + lk * 8]);
      #pragma unroll
      for (int nt = 0; nt < 12; nt++){
        int n0 = nh * 192 + nt * 16;
        ffacc[nt] = __builtin_amdgcn_mfma_f32_16x16x32_bf16(
                      a2, ldfrag(&w2[(size_t)(n0 + lr) * FFH + fc * 256 + kk * 32 + lk * 8]),
                      ffacc[nt], 0, 0, 0);
      }
    }
    __syncthreads();
  }

  // + b2 + residual (global re-read) -> pre-LN3, kept in ffacc
  #pragma unroll
  for (int nt = 0; nt < 12; nt++){
    int c = nh * 192 + nt * 16 + lr;
    float b2v = ffn_b2[c];
    #pragma unroll
    for (int r = 0; r < 4; r++){
      int row = m0 + lk * 4 + r;
      ffacc[nt][r] += b2v + b2f(hg[(t0 + row) * DD + c]);
    }
  }

  // LN3 partial stats: reduce over this wave's 192 cols (12 nt x 16 lr)
  float s1[4], s2[4];
  #pragma unroll
  for (int r = 0; r < 4; r++){ s1[r] = 0.f; s2[r] = 0.f; }
  #pragma unroll
  for (int nt = 0; nt < 12; nt++)
    #pragma unroll
    for (int r = 0; r < 4; r++){ float v = ffacc[nt][r]; s1[r] += v; s2[r] += v * v; }
  #pragma unroll
  for (int off = 1; off < 16; off <<= 1)
    #pragma unroll
    for (int r = 0; r < 4; r++){ s1[r] += __shfl_xor(s1[r], off); s2[r] += __shfl_xor(s2[r], off); }
  __syncthreads();   // tcb dead -> pst overlay safe
  if (lr == 0){
    #pragma unroll
    for (int r = 0; r < 4; r++){
      int row = m0 + lk * 4 + r;
      pst[row * 4 + nh * 2 + 0] = s1[r];
      pst[row * 4 + nh * 2 + 1] = s2[r];
    }
  }
  __syncthreads();

  // finish LN3 + pool over L=4 (lane's 4 rows = one batch) -> pf/pb
  {
    float mean[4], rstd[4];
    #pragma unroll
    for (int r = 0; r < 4; r++){
      int row = m0 + lk * 4 + r;
      float t1 = pst[row * 4 + 0] + pst[row * 4 + 2];
      float t2 = pst[row * 4 + 1] + pst[row * 4 + 3];
      mean[r] = t1 * (1.f / DD);
      float var = t2 * (1.f / DD) - mean[r] * mean[r];
      rstd[r] = rsqrtf(var + EPS);
    }
    int batch = (m0 >> 2) + lk;     // rows m0+lk*4 .. +3 = one batch
    #pragma unroll
    for (int nt = 0; nt < 12; nt++){
      int c = nh * 192 + nt * 16 + lr;
      float g3 = n3g[c], b3 = n3b[c];
      float p = 0.f;
      #pragma unroll
      for (int r = 0; r < 4; r++)
        p += 0.25f * ((ffacc[nt][r] - mean[r]) * rstd[r] * g3 + b3);
      pf[batch * LDPF + c] = p;
      pb[batch * LDPB + c] = f2b(p);
    }
  }
  __syncthreads();

  // gate gemm (M=16) + sigmoid + multiply + store fp32
  {
    bf16x8 ag[12];
    const u16* ap = &pb[lr * LDPB + lk * 8];
    #pragma unroll
    for (int kk = 0; kk < 12; kk++) ag[kk] = ldfrag(ap + kk * 32);
    for (int nt = w * 3; nt < w * 3 + 3; nt++){
      int n0 = nt * 16;
      f32x4 acc = {0.f, 0.f, 0.f, 0.f};
      const u16* bp = &wg[(size_t)(n0 + lr) * DD + lk * 8];
      #pragma unroll
      for (int kk = 0; kk < 12; kk++)
        acc = __builtin_amdgcn_mfma_f32_16x16x32_bf16(ag[kk], ldfrag(bp + kk * 32), acc, 0, 0, 0);
      float gbv = gate_b[n0 + lr];
      #pragma unroll
      for (int r = 0; r < 4; r++){
        int batch = lk * 4 + r;
        float g = 1.f / (1.f + expf(-(acc[r] + gbv)));
        out[(size_t)(b0 + batch) * DD + n0 + lr] = pf[batch * LDPF + n0 + lr] * g;
      }
    }
  }
}

// ---------------------------------------------------------------------------
// host launch
// ---------------------------------------------------------------------------
#define OFF_WV     0
#define OFF_WOUT   147456
#define OFF_SAWIN  294912
#define OFF_SAWOUT 737280
#define OFF_W1     884736
#define OFF_W2     1474560
#define OFF_WG     2064384
#define OFF_H      2211840   // ushort index; h buffer: 32768*4*384 bf16

extern "C" void kernel_launch(void* const* d_in, const int* in_sizes, int n_in,
                              void* d_out, int out_size, void* d_ws, size_t ws_size,
                              hipStream_t stream)
{
  const float* x        = (const float*)d_in[0];
  const float* latents  = (const float*)d_in[1];
  const float* ca_w_in  = (const float*)d_in[2];
  const float* ca_b_in  = (const float*)d_in[3];
  const float* ca_w_out = (const float*)d_in[4];
  const float* ca_b_out = (const float*)d_in[5];
  const float* sa_w_in  = (const float*)d_in[6];
  const float* sa_b_in  = (const float*)d_in[7];
  const float* sa_w_out = (const float*)d_in[8];
  const float* sa_b_out = (const float*)d_in[9];
  const float* n1g = (const float*)d_in[10];
  const float* n1b = (const float*)d_in[11];
  const float* n2g = (const float*)d_in[12];
  const float* n2b = (const float*)d_in[13];
  const float* n3g = (const float*)d_in[14];
  const float* n3b = (const float*)d_in[15];
  const float* w1f = (const float*)d_in[16];
  const float* b1  = (const float*)d_in[17];
  const float* w2f = (const float*)d_in[18];
  const float* b2  = (const float*)d_in[19];
  const float* wgf = (const float*)d_in[20];
  const float* gb  = (const float*)d_in[21];

  u16* ws = (u16*)d_ws;
  u16* wv     = ws + OFF_WV;
  u16* wout   = ws + OFF_WOUT;
  u16* sawin  = ws + OFF_SAWIN;
  u16* sawout = ws + OFF_SAWOUT;
  u16* w1     = ws + OFF_W1;
  u16* w2     = ws + OFF_W2;
  u16* wg     = ws + OFF_WG;
  u16* h      = ws + OFF_H;

  wconv<<<dim3((147456 + 255) / 256), dim3(256), 0, stream>>>(ca_w_in + 768 * 384, wv, 147456);
  wconv<<<dim3((147456 + 255) / 256), dim3(256), 0, stream>>>(ca_w_out, wout, 147456);
  wconv<<<dim3((442368 + 255) / 256), dim3(256), 0, stream>>>(sa_w_in, sawin, 442368);
  wconv<<<dim3((147456 + 255) / 256), dim3(256), 0, stream>>>(sa_w_out, sawout, 147456);
  wconv<<<dim3((589824 + 255) / 256), dim3(256), 0, stream>>>(w1f, w1, 589824);
  wconv<<<dim3((589824 + 255) / 256), dim3(256), 0, stream>>>(w2f, w2, 589824);
  wconv<<<dim3((147456 + 255) / 256), dim3(256), 0, stream>>>(wgf, wg, 147456);

  const int SM1 = 64 * LDA * 2;                                  // 50176
  const int SM2 = 3 * 64 * LDQ * 2 + 64 * LDA * 2;               // 71680
  const int SM3 = 1024 + 16 * LDPF * 4 + 16 * LDPB * 2;          // 38400 (tcb 33280 overlays)
  const int SM3r = (SM3 > 64 * LDF * 2) ? SM3 : 64 * LDF * 2;
  (void)hipFuncSetAttribute((const void*)k1_ca,  hipFuncAttributeMaxDynamicSharedMemorySize, SM1);
  (void)hipFuncSetAttribute((const void*)k2_sa,  hipFuncAttributeMaxDynamicSharedMemorySize, SM2);
  (void)hipFuncSetAttribute((const void*)k3_ffn, hipFuncAttributeMaxDynamicSharedMemorySize, SM3r);

  k1_ca<<<dim3(512),  dim3(512), SM1, stream>>>(x, latents, ca_b_in, ca_b_out, n1g, n1b, wv, wout, h);
  k2_sa<<<dim3(2048), dim3(512), SM2, stream>>>(sa_b_in, sa_b_out, n2g, n2b, sawin, sawout, h);
  k3_ffn<<<dim3(2048), dim3(512), SM3r, stream>>>(b1, b2, n3g, n3b, gb, w1, w2, wg, h, (float*)d_out);

  (void)in_sizes; (void)n_in; (void)out_size; (void)ws_size;
}

// Round 5
// 2509.516 us; speedup vs baseline: 1.8467x; 1.8425x over previous
//
#include <hip/hip_runtime.h>
#include <hip/hip_bf16.h>
#include <math.h>

// Problem dims
#define DD 384
#define NHD 8
#define DHD 48
#define LL 4
#define NB 32768
#define FFH 1536
#define LDA 392   // k1 LDS stride (free-ish b128 banks)
#define LDQ 56    // k2 qkv bf16 stride
#define LDPB 392  // pooled bf16 stride
#define LDPF 388  // pooled fp32 stride
#define EPS 1e-5f

typedef short bf16x8 __attribute__((ext_vector_type(8)));
typedef float f32x4 __attribute__((ext_vector_type(4)));
typedef unsigned short u16;
typedef unsigned int u32;

__device__ __forceinline__ u16 f2b(float f){           // fp32 -> bf16 RNE
  u32 u = __builtin_bit_cast(u32, f);
  u += 0x7FFFu + ((u >> 16) & 1u);
  return (u16)(u >> 16);
}
__device__ __forceinline__ float b2f(u16 h){ u32 u = ((u32)h) << 16; return __builtin_bit_cast(float, u); }

__device__ __forceinline__ bf16x8 ldfrag(const u16* p){
  uint4 q = *reinterpret_cast<const uint4*>(p);
  return __builtin_bit_cast(bf16x8, q);
}

// async global -> LDS, 16B per lane; dest = wave-uniform base + lane*16
__device__ __forceinline__ void gll16(const void* g, char* l){
  __builtin_amdgcn_global_load_lds((const __attribute__((address_space(1))) unsigned int*)g,
                                   (__attribute__((address_space(3))) unsigned int*)l, 16, 0, 0);
}

// fp32 -> bf16 weight conversion (prepass; weights stay hot in L2/L3)
extern "C" __global__ void wconv(const float* __restrict__ src, u16* __restrict__ dst, int n){
  int i = blockIdx.x * 256 + threadIdx.x;
  if (i < n) dst[i] = f2b(src[i]);
}

// ---------------------------------------------------------------------------
// K1: cross-attn collapses to  h1[b,l,:] = LN1( (x@wv^T+bv)@wout^T+bout + lat[l] )
// ---------------------------------------------------------------------------
extern "C" __global__ void __launch_bounds__(512, 4)
k1_ca(const float* __restrict__ x, const float* __restrict__ latents,
      const float* __restrict__ ca_b_in, const float* __restrict__ ca_b_out,
      const float* __restrict__ n1g, const float* __restrict__ n1b,
      const u16* __restrict__ wv, const u16* __restrict__ wout,
      u16* __restrict__ h1g)
{
  extern __shared__ char smem[];
  u16* xb = (u16*)smem;           // [64][LDA], reused for v then ca
  const int tid = threadIdx.x, lane = tid & 63, w = tid >> 6;
  const int lr = lane & 15, lk = lane >> 4;
  const int b0 = blockIdx.x * 64;

  for (int i = tid; i < 64 * 96; i += 512){
    int r = i / 96, c4 = i % 96;
    float4 f = reinterpret_cast<const float4*>(x + (size_t)(b0 + r) * DD)[c4];
    u16* d = &xb[r * LDA + c4 * 4];
    d[0] = f2b(f.x); d[1] = f2b(f.y); d[2] = f2b(f.z); d[3] = f2b(f.w);
  }
  __syncthreads();

  const int m0 = (w & 3) * 16, nh = w >> 2;

  {
    bf16x8 af[12];
    const u16* ap = &xb[(m0 + lr) * LDA + lk * 8];
    #pragma unroll
    for (int kk = 0; kk < 12; kk++) af[kk] = ldfrag(ap + kk * 32);
    __syncthreads();
    for (int nt = nh * 12; nt < nh * 12 + 12; nt++){
      int n0 = nt * 16;
      f32x4 acc = {0.f, 0.f, 0.f, 0.f};
      const u16* bp = &wv[(size_t)(n0 + lr) * DD + lk * 8];
      #pragma unroll
      for (int kk = 0; kk < 12; kk++)
        acc = __builtin_amdgcn_mfma_f32_16x16x32_bf16(af[kk], ldfrag(bp + kk * 32), acc, 0, 0, 0);
      float bias = ca_b_in[768 + n0 + lr];
      #pragma unroll
      for (int r = 0; r < 4; r++)
        xb[(m0 + lk * 4 + r) * LDA + n0 + lr] = f2b(acc[r] + bias);
    }
  }
  __syncthreads();
  {
    bf16x8 af[12];
    const u16* ap = &xb[(m0 + lr) * LDA + lk * 8];
    #pragma unroll
    for (int kk = 0; kk < 12; kk++) af[kk] = ldfrag(ap + kk * 32);
    __syncthreads();
    for (int nt = nh * 12; nt < nh * 12 + 12; nt++){
      int n0 = nt * 16;
      f32x4 acc = {0.f, 0.f, 0.f, 0.f};
      const u16* bp = &wout[(size_t)(n0 + lr) * DD + lk * 8];
      #pragma unroll
      for (int kk = 0; kk < 12; kk++)
        acc = __builtin_amdgcn_mfma_f32_16x16x32_bf16(af[kk], ldfrag(bp + kk * 32), acc, 0, 0, 0);
      float bias = ca_b_out[n0 + lr];
      #pragma unroll
      for (int r = 0; r < 4; r++)
        xb[(m0 + lk * 4 + r) * LDA + n0 + lr] = f2b(acc[r] + bias);
    }
  }
  __syncthreads();

  for (int idx = w; idx < 64 * LL; idx += 8){
    int l = idx >> 6, r = idx & 63;
    float vals[6]; float s1 = 0.f, s2 = 0.f;
    #pragma unroll
    for (int j = 0; j < 6; j++){
      int c = lane + 64 * j;
      float xv = b2f(xb[r * LDA + c]) + latents[l * DD + c];
      vals[j] = xv; s1 += xv; s2 += xv * xv;
    }
    #pragma unroll
    for (int off = 32; off > 0; off >>= 1){ s1 += __shfl_xor(s1, off); s2 += __shfl_xor(s2, off); }
    float mean = s1 * (1.f / DD);
    float var  = s2 * (1.f / DD) - mean * mean;
    float rstd = rsqrtf(var + EPS);
    size_t orow = ((size_t)(b0 + r) * LL + l) * DD;
    #pragma unroll
    for (int j = 0; j < 6; j++){
      int c = lane + 64 * j;
      h1g[orow + c] = f2b((vals[j] - mean) * rstd * n1g[c] + n1b[c]);
    }
  }
}

// ---------------------------------------------------------------------------
// K2: self-attn over L=4 + out-proj + residual + LN2 (in place on hg)
// QKV weights staged per head via global_load_lds (9 KB tiles, double-buffered,
// XOR-swizzled source so ds_read_b128 is bank-conflict-free).
// Out-proj accumulated per head (K=48 as 32+16 with zero-filled A tail).
// ---------------------------------------------------------------------------
extern "C" __global__ void __launch_bounds__(512, 4)
k2_sa(const float* __restrict__ sa_b_in, const float* __restrict__ sa_b_out,
      const float* __restrict__ n2g, const float* __restrict__ n2b,
      const u16* __restrict__ wqkv, const u16* __restrict__ wo,
      u16* __restrict__ hg)
{
  extern __shared__ char smem[];
  u16* qb = (u16*)smem;                    // [64][56]
  u16* kb = qb + 64 * LDQ;
  u16* vb = kb + 64 * LDQ;
  u16* ohp = vb + 64 * LDQ;                // [64][56] attn output
  char* RB2 = smem + 28672;                // stage dbuf 2 x 9216
  u16* st = (u16*)smem;                    // [64][392] LN staging overlay
  const int tid = threadIdx.x, lane = tid & 63, w = tid >> 6;
  const int lr = lane & 15, lk = lane >> 4;
  const int b0 = blockIdx.x * 16;
  const size_t t0 = (size_t)b0 * 4;
  const int m0 = (w & 3) * 16, ng = w >> 2;
  const char* wqb = (const char*)wqkv;

  // staging source precompute: tile rows 0..143 = q48|k48|v48 of one head
  u32 soQ0, soQ1;
  {
    int D = tid * 16;
    int P = D ^ (((D >> 7) & 3) << 4);
    int rho = P >> 6, cb = P & 63;
    soQ0 = (u32)(((rho / 48) * 384 + (rho % 48)) * 768 + cb);
    D = 8192 + tid * 16;                  // only wave 0 uses this
    P = D ^ (((D >> 7) & 3) << 4);
    rho = P >> 6; if (rho > 143) rho = 143;
    cb = P & 63;
    soQ1 = (u32)(((rho / 48) * 384 + (rho % 48)) * 768 + cb);
  }
  auto stageQ = [&](int slot, int hh, int kk){
    gll16(wqb + soQ0 + hh * 36864 + kk * 64, RB2 + slot * 9216 + w * 1024);
    if (w == 0)
      gll16(wqb + soQ1 + hh * 36864 + kk * 64, RB2 + slot * 9216 + 8192);
  };
  // ds_read fragment base: row0 = lr (nt shifts +1024 bytes each)
  const int offQ0 = (lr * 64 + lk * 16) ^ (((lr >> 1) & 3) << 4);

  bf16x8 af[12];          // h1 M-tile fragments straight from global
  { const u16* ap = &hg[(t0 + m0 + lr) * DD + lk * 8];
    #pragma unroll
    for (int kk = 0; kk < 12; kk++) af[kk] = ldfrag(ap + kk * 32); }

  f32x4 oacc[12];
  #pragma unroll
  for (int i = 0; i < 12; i++) oacc[i] = {0.f, 0.f, 0.f, 0.f};

  stageQ(0, 0, 0);
  __syncthreads();

  for (int hh = 0; hh < NHD; hh++){
    // QKV GEMM: 12 K-steps, 2-phase staged pipeline
    f32x4 acc[5];
    #pragma unroll
    for (int i = 0; i < 5; i++) acc[i] = {0.f, 0.f, 0.f, 0.f};
    int p = 0;
    for (int kk = 0; kk < 12; kk++){
      if (kk < 11) stageQ(p ^ 1, hh, kk + 1);
      const char* bb = RB2 + p * 9216;
      #pragma unroll
      for (int i = 0; i < 5; i++){
        int nt = ng + i * 2;
        if (nt < 9){
          bf16x8 bf = ldfrag((const u16*)(bb + offQ0 + nt * 1024));
          acc[i] = __builtin_amdgcn_mfma_f32_16x16x32_bf16(af[kk], bf, acc[i], 0, 0, 0);
        }
      }
      __syncthreads();
      p ^= 1;
    }
    if (hh < 7) stageQ(0, hh + 1, 0);   // overlap next head's staging with epilogue+attention

    // epilogue: write q/k/v bf16
    #pragma unroll
    for (int i = 0; i < 5; i++){
      int nt = ng + i * 2;
      if (nt < 9){
        int op = nt / 3, sub = nt % 3;
        float bias = sa_b_in[op * 384 + hh * 48 + sub * 16 + lr];
        u16* dst = (op == 0) ? qb : (op == 1) ? kb : vb;
        int c = sub * 16 + lr;
        #pragma unroll
        for (int r = 0; r < 4; r++)
          dst[(m0 + lk * 4 + r) * LDQ + c] = f2b(acc[i][r] + bias);
      }
    }
    __syncthreads();

    // tiny attention: 32 threads per batch
    {
      int tb = tid >> 5, t = tid & 31;
      int qr = t & 3, cg = t >> 2;
      int rq = tb * 4 + qr;
      const float scale = 0.14433756729740643f;  // 1/sqrt(48)
      float s[4];
      #pragma unroll
      for (int kl = 0; kl < 4; kl++){
        float a = 0.f;
        const u16* qp = &qb[rq * LDQ];
        const u16* kp = &kb[(tb * 4 + kl) * LDQ];
        #pragma unroll
        for (int d2 = 0; d2 < 24; d2++){
          u32 qu = *reinterpret_cast<const u32*>(qp + 2 * d2);
          u32 ku = *reinterpret_cast<const u32*>(kp + 2 * d2);
          a += b2f((u16)qu) * b2f((u16)ku) + b2f((u16)(qu >> 16)) * b2f((u16)(ku >> 16));
        }
        s[kl] = a * scale;
      }
      float m = fmaxf(fmaxf(s[0], s[1]), fmaxf(s[2], s[3]));
      float e0 = expf(s[0] - m), e1 = expf(s[1] - m), e2 = expf(s[2] - m), e3 = expf(s[3] - m);
      float rs = 1.f / (e0 + e1 + e2 + e3);
      #pragma unroll
      for (int cc = 0; cc < 6; cc++){
        int c = cg * 6 + cc;
        float o = e0 * rs * b2f(vb[(tb * 4 + 0) * LDQ + c]) + e1 * rs * b2f(vb[(tb * 4 + 1) * LDQ + c])
                + e2 * rs * b2f(vb[(tb * 4 + 2) * LDQ + c]) + e3 * rs * b2f(vb[(tb * 4 + 3) * LDQ + c]);
        ohp[rq * LDQ + c] = f2b(o);
      }
    }
    __syncthreads();

    // out-proj accumulate for this head: K=48 = 32 + 16(zero-padded A tail)
    {
      bf16x8 z = {0, 0, 0, 0, 0, 0, 0, 0};
      bf16x8 a0 = ldfrag(&ohp[(m0 + lr) * LDQ + lk * 8]);
      bf16x8 a1 = (lk < 2) ? ldfrag(&ohp[(m0 + lr) * LDQ + 32 + lk * 8]) : z;
      #pragma unroll
      for (int nt = 0; nt < 12; nt++){
        int n0 = ng * 192 + nt * 16;
        const u16* bp = &wo[(size_t)(n0 + lr) * DD + hh * 48];
        oacc[nt] = __builtin_amdgcn_mfma_f32_16x16x32_bf16(a0, ldfrag(bp + lk * 8), oacc[nt], 0, 0, 0);
        bf16x8 b1 = (lk < 2) ? ldfrag(bp + 32 + lk * 8) : z;
        oacc[nt] = __builtin_amdgcn_mfma_f32_16x16x32_bf16(a1, b1, oacc[nt], 0, 0, 0);
      }
    }
    __syncthreads();
  }

  // + bias + residual (global re-read) -> st overlay
  #pragma unroll
  for (int nt = 0; nt < 12; nt++){
    int c = ng * 192 + nt * 16 + lr;
    float bias = sa_b_out[c];
    #pragma unroll
    for (int r = 0; r < 4; r++){
      int row = m0 + lk * 4 + r;
      float v = oacc[nt][r] + bias + b2f(hg[(t0 + row) * DD + c]);
      st[row * 392 + c] = f2b(v);
    }
  }
  __syncthreads();
  // LN2 -> global
  for (int r = w; r < 64; r += 8){
    float vals[6]; float s1 = 0.f, s2 = 0.f;
    #pragma unroll
    for (int j = 0; j < 6; j++){
      int c = lane + 64 * j;
      float xv = b2f(st[r * 392 + c]);
      vals[j] = xv; s1 += xv; s2 += xv * xv;
    }
    #pragma unroll
    for (int off = 32; off > 0; off >>= 1){ s1 += __shfl_xor(s1, off); s2 += __shfl_xor(s2, off); }
    float mean = s1 * (1.f / DD), var = s2 * (1.f / DD) - mean * mean, rstd = rsqrtf(var + EPS);
    #pragma unroll
    for (int j = 0; j < 6; j++){
      int c = lane + 64 * j;
      hg[(t0 + r) * DD + c] = f2b((vals[j] - mean) * rstd * n2g[c] + n2b[c]);
    }
  }
}

// ---------------------------------------------------------------------------
// K3: FFN + LN3 + pool + gate.  w1/w2 K-slices staged via global_load_lds
// (dbuf, XOR-swizzled source + reads).  tcb stride-256 swizzled (full-address
// XOR on BOTH write and read -- R4 bug was XOR-before-add on the read).
// ---------------------------------------------------------------------------
extern "C" __global__ void __launch_bounds__(512, 4)
k3_ffn(const float* __restrict__ ffn_b1, const float* __restrict__ ffn_b2,
       const float* __restrict__ n3g, const float* __restrict__ n3b,
       const float* __restrict__ gate_b,
       const u16* __restrict__ w1, const u16* __restrict__ w2, const u16* __restrict__ wg,
       const u16* __restrict__ hg, float* __restrict__ out)
{
  extern __shared__ char smem[];
  // tcb: [0, 32768) swizzled [64][256]; RB: [32768, 81920) staging
  char* RB = smem + 32768;
  float* pst = (float*)RB;                         // [64][4]   (overlay, post-GEMM)
  float* pf  = (float*)(RB + 1024);                // [16][388]
  u16*   pb  = (u16*)(RB + 1024 + 16 * LDPF * 4);  // [16][392]
  const int tid = threadIdx.x, lane = tid & 63, w = tid >> 6;
  const int lr = lane & 15, lk = lane >> 4;
  const int b0 = blockIdx.x * 16;
  const size_t t0 = (size_t)b0 * 4;
  const int m0 = (w & 3) * 16, nh = w >> 2;
  const char* w1b = (const char*)w1;
  const char* w2b = (const char*)w2;

  // staging source offsets (row*rowbytes + colbyte), swizzle-consistent
  u32 soA[2], soB[3];
  #pragma unroll
  for (int j = 0; j < 2; j++){
    int D = j * 8192 + tid * 16;
    int P = D ^ (((D >> 7) & 3) << 4);
    soA[j] = (u32)((P >> 6) * 768 + (P & 63));       // w1 row stride 768 B
  }
  #pragma unroll
  for (int j = 0; j < 3; j++){
    int D = j * 8192 + tid * 16;
    int P = D ^ (((D >> 7) & 3) << 4);
    soB[j] = (u32)((P >> 6) * 3072 + (P & 63));      // w2 row stride 3072 B
  }
  auto stageA = [&](int slot, int fc, int kk){
    #pragma unroll
    for (int j = 0; j < 2; j++)
      gll16(w1b + (size_t)fc * 196608 + kk * 64 + soA[j],
            RB + slot * 16384 + j * 8192 + w * 1024);
  };
  auto stageB = [&](int slot, int fc, int kk){
    #pragma unroll
    for (int j = 0; j < 3; j++)
      gll16(w2b + (size_t)fc * 512 + kk * 64 + soB[j],
            RB + slot * 24576 + j * 8192 + w * 1024);
  };

  // ds_read bases (t/nt shift = +1024 bytes, swizzle-invariant: masks at bits
  // 4-5, shifts at bits >=10)
  const int rA0 = nh * 128 + lr;
  const int offA0 = (rA0 * 64 + lk * 16) ^ (((rA0 >> 1) & 3) << 4);
  const int rB0 = nh * 192 + lr;
  const int offB0 = (rB0 * 64 + lk * 16) ^ (((rB0 >> 1) & 3) << 4);
  const int rT = m0 + lr;

  bf16x8 af[12];                       // A-frags: hg read ONCE
  { const u16* ap = &hg[(t0 + m0 + lr) * DD + lk * 8];
    #pragma unroll
    for (int kk = 0; kk < 12; kk++) af[kk] = ldfrag(ap + kk * 32); }

  f32x4 ffacc[12];
  #pragma unroll
  for (int i = 0; i < 12; i++) ffacc[i] = {0.f, 0.f, 0.f, 0.f};

  stageA(0, 0, 0);
  __syncthreads();

  for (int fc = 0; fc < 6; fc++){
    // GEMM-A: tacc = h @ w1_chunk^T  (12 K-steps, 2-phase)
    f32x4 tacc[8];
    #pragma unroll
    for (int i = 0; i < 8; i++) tacc[i] = {0.f, 0.f, 0.f, 0.f};
    int pa = 0;
    for (int kk = 0; kk < 12; kk++){
      if (kk < 11) stageA(pa ^ 1, fc, kk + 1);
      const char* bb = RB + pa * 16384;
      #pragma unroll
      for (int t = 0; t < 8; t++){
        bf16x8 bf = ldfrag((const u16*)(bb + offA0 + t * 1024));
        tacc[t] = __builtin_amdgcn_mfma_f32_16x16x32_bf16(af[kk], bf, tacc[t], 0, 0, 0);
      }
      __syncthreads();
      pa ^= 1;
    }
    stageB(0, fc, 0);                  // overlaps with gelu epilogue
    // gelu epilogue -> tcb (swizzled, full-address XOR)
    #pragma unroll
    for (int t = 0; t < 8; t++){
      int cl = (nh * 8 + t) * 16 + lr;
      float bias = ffn_b1[fc * 256 + cl];
      #pragma unroll
      for (int r = 0; r < 4; r++){
        float v = tacc[t][r] + bias;
        float g = 0.5f * v * (1.f + erff(v * 0.70710678118f));
        int rw = m0 + lk * 4 + r;
        int T = rw * 512 + cl * 2;
        *(u16*)(smem + (T ^ ((rw & 7) << 4))) = f2b(g);
      }
    }
    __syncthreads();
    // GEMM-B: ffacc += gelu @ w2_chunk^T  (8 K-steps, 2-phase)
    int pbs = 0;
    for (int kk = 0; kk < 8; kk++){
      if (kk < 7) stageB(pbs ^ 1, fc, kk + 1);
      else if (fc < 5) stageA(0, fc + 1, 0);
      const char* bb = RB + pbs * 24576;
      // FIX (R4 bug): full-address XOR, matching the write's involution.
      bf16x8 a2 = ldfrag((const u16*)(smem + ((rT * 512 + kk * 64 + lk * 16) ^ ((rT & 7) << 4))));
      #pragma unroll
      for (int nt = 0; nt < 12; nt++){
        bf16x8 bf = ldfrag((const u16*)(bb + offB0 + nt * 1024));
        ffacc[nt] = __builtin_amdgcn_mfma_f32_16x16x32_bf16(a2, bf, ffacc[nt], 0, 0, 0);
      }
      __syncthreads();
      pbs ^= 1;
    }
  }

  // + b2 + residual (global re-read), kept in ffacc
  #pragma unroll
  for (int nt = 0; nt < 12; nt++){
    int c = nh * 192 + nt * 16 + lr;
    float b2v = ffn_b2[c];
    #pragma unroll
    for (int r = 0; r < 4; r++){
      int row = m0 + lk * 4 + r;
      ffacc[nt][r] += b2v + b2f(hg[(t0 + row) * DD + c]);
    }
  }

  // LN3 partial stats (wave covers 192 cols per row)
  float s1[4], s2[4];
  #pragma unroll
  for (int r = 0; r < 4; r++){ s1[r] = 0.f; s2[r] = 0.f; }
  #pragma unroll
  for (int nt = 0; nt < 12; nt++)
    #pragma unroll
    for (int r = 0; r < 4; r++){ float v = ffacc[nt][r]; s1[r] += v; s2[r] += v * v; }
  #pragma unroll
  for (int off = 1; off < 16; off <<= 1)
    #pragma unroll
    for (int r = 0; r < 4; r++){ s1[r] += __shfl_xor(s1[r], off); s2[r] += __shfl_xor(s2[r], off); }
  if (lr == 0){
    #pragma unroll
    for (int r = 0; r < 4; r++){
      int row = m0 + lk * 4 + r;
      pst[row * 4 + nh * 2 + 0] = s1[r];
      pst[row * 4 + nh * 2 + 1] = s2[r];
    }
  }
  __syncthreads();

  // finish LN3 + pool over L=4 -> pf/pb
  {
    float mean[4], rstd[4];
    #pragma unroll
    for (int r = 0; r < 4; r++){
      int row = m0 + lk * 4 + r;
      float u1 = pst[row * 4 + 0] + pst[row * 4 + 2];
      float u2 = pst[row * 4 + 1] + pst[row * 4 + 3];
      mean[r] = u1 * (1.f / DD);
      float var = u2 * (1.f / DD) - mean[r] * mean[r];
      rstd[r] = rsqrtf(var + EPS);
    }
    int batch = (m0 >> 2) + lk;
    #pragma unroll
    for (int nt = 0; nt < 12; nt++){
      int c = nh * 192 + nt * 16 + lr;
      float g3 = n3g[c], b3 = n3b[c];
      float pv = 0.f;
      #pragma unroll
      for (int r = 0; r < 4; r++)
        pv += 0.25f * ((ffacc[nt][r] - mean[r]) * rstd[r] * g3 + b3);
      pf[batch * LDPF + c] = pv;
      pb[batch * LDPB + c] = f2b(pv);
    }
  }
  __syncthreads();

  // gate gemm (M=16) + sigmoid + multiply + store fp32
  {
    bf16x8 ag[12];
    const u16* ap = &pb[lr * LDPB + lk * 8];
    #pragma unroll
    for (int kk = 0; kk < 12; kk++) ag[kk] = ldfrag(ap + kk * 32);
    for (int nt = w * 3; nt < w * 3 + 3; nt++){
      int n0 = nt * 16;
      f32x4 acc = {0.f, 0.f, 0.f, 0.f};
      const u16* bp = &wg[(size_t)(n0 + lr) * DD + lk * 8];
      #pragma unroll
      for (int kk = 0; kk < 12; kk++)
        acc = __builtin_amdgcn_mfma_f32_16x16x32_bf16(ag[kk], ldfrag(bp + kk * 32), acc, 0, 0, 0);
      float gbv = gate_b[n0 + lr];
      #pragma unroll
      for (int r = 0; r < 4; r++){
        int batch = lk * 4 + r;
        float g = 1.f / (1.f + expf(-(acc[r] + gbv)));
        out[(size_t)(b0 + batch) * DD + n0 + lr] = pf[batch * LDPF + n0 + lr] * g;
      }
    }
  }
}

// ---------------------------------------------------------------------------
// host launch
// ---------------------------------------------------------------------------
#define OFF_WV     0
#define OFF_WOUT   147456
#define OFF_SAWIN  294912
#define OFF_SAWOUT 737280
#define OFF_W1     884736
#define OFF_W2     1474560
#define OFF_WG     2064384
#define OFF_H      2211840   // ushort index; h buffer: 32768*4*384 bf16

extern "C" void kernel_launch(void* const* d_in, const int* in_sizes, int n_in,
                              void* d_out, int out_size, void* d_ws, size_t ws_size,
                              hipStream_t stream)
{
  const float* x        = (const float*)d_in[0];
  const float* latents  = (const float*)d_in[1];
  const float* ca_w_in  = (const float*)d_in[2];
  const float* ca_b_in  = (const float*)d_in[3];
  const float* ca_w_out = (const float*)d_in[4];
  const float* ca_b_out = (const float*)d_in[5];
  const float* sa_w_in  = (const float*)d_in[6];
  const float* sa_b_in  = (const float*)d_in[7];
  const float* sa_w_out = (const float*)d_in[8];
  const float* sa_b_out = (const float*)d_in[9];
  const float* n1g = (const float*)d_in[10];
  const float* n1b = (const float*)d_in[11];
  const float* n2g = (const float*)d_in[12];
  const float* n2b = (const float*)d_in[13];
  const float* n3g = (const float*)d_in[14];
  const float* n3b = (const float*)d_in[15];
  const float* w1f = (const float*)d_in[16];
  const float* b1  = (const float*)d_in[17];
  const float* w2f = (const float*)d_in[18];
  const float* b2  = (const float*)d_in[19];
  const float* wgf = (const float*)d_in[20];
  const float* gb  = (const float*)d_in[21];

  u16* ws = (u16*)d_ws;
  u16* wv     = ws + OFF_WV;
  u16* wout   = ws + OFF_WOUT;
  u16* sawin  = ws + OFF_SAWIN;
  u16* sawout = ws + OFF_SAWOUT;
  u16* w1     = ws + OFF_W1;
  u16* w2     = ws + OFF_W2;
  u16* wg     = ws + OFF_WG;
  u16* h      = ws + OFF_H;

  wconv<<<dim3((147456 + 255) / 256), dim3(256), 0, stream>>>(ca_w_in + 768 * 384, wv, 147456);
  wconv<<<dim3((147456 + 255) / 256), dim3(256), 0, stream>>>(ca_w_out, wout, 147456);
  wconv<<<dim3((442368 + 255) / 256), dim3(256), 0, stream>>>(sa_w_in, sawin, 442368);
  wconv<<<dim3((147456 + 255) / 256), dim3(256), 0, stream>>>(sa_w_out, sawout, 147456);
  wconv<<<dim3((589824 + 255) / 256), dim3(256), 0, stream>>>(w1f, w1, 589824);
  wconv<<<dim3((589824 + 255) / 256), dim3(256), 0, stream>>>(w2f, w2, 589824);
  wconv<<<dim3((147456 + 255) / 256), dim3(256), 0, stream>>>(wgf, wg, 147456);

  const int SM1 = 64 * LDA * 2;     // 50176
  const int SM2 = 64 * 392 * 2;     // 50176 (qkv+oh+dbuf union'd under LN staging)
  const int SM3 = 32768 + 49152;    // 81920: tcb + staging region
  (void)hipFuncSetAttribute((const void*)k1_ca,  hipFuncAttributeMaxDynamicSharedMemorySize, SM1);
  (void)hipFuncSetAttribute((const void*)k2_sa,  hipFuncAttributeMaxDynamicSharedMemorySize, SM2);
  (void)hipFuncSetAttribute((const void*)k3_ffn, hipFuncAttributeMaxDynamicSharedMemorySize, SM3);

  k1_ca<<<dim3(512),  dim3(512), SM1, stream>>>(x, latents, ca_b_in, ca_b_out, n1g, n1b, wv, wout, h);
  k2_sa<<<dim3(2048), dim3(512), SM2, stream>>>(sa_b_in, sa_b_out, n2g, n2b, sawin, sawout, h);
  k3_ffn<<<dim3(2048), dim3(512), SM3, stream>>>(b1, b2, n3g, n3b, gb, w1, w2, wg, h, (float*)d_out);

  (void)in_sizes; (void)n_in; (void)out_size; (void)ws_size;
}